// Round 1
// baseline (676.912 us; speedup 1.0000x reference)
//
#include <hip/hip_runtime.h>
#include <hip/hip_bf16.h>
#include <cstdint>
#include <cstddef>

#define N_TOK 16384
#define DIM   1024
#define NEXP  64
#define CAPACITY 640

typedef __bf16 bf16x8 __attribute__((ext_vector_type(8)));
typedef float  f32x4  __attribute__((ext_vector_type(4)));

__device__ __forceinline__ unsigned short f2bf(float f) {
    union { float f; unsigned int u; } a; a.f = f;
    unsigned int r = a.u + 0x7FFFu + ((a.u >> 16) & 1u);  // RTNE
    return (unsigned short)(r >> 16);
}

// ---------------------------------------------------------------------------
// Phase 1: router GEMM (fp32) + top-2 + softmax gates + x -> bf16 conversion.
// Block = 256 threads handles 64 tokens x 64 experts. K-tiled by 64.
// ---------------------------------------------------------------------------
__global__ __launch_bounds__(256) void router_kernel(
    const float* __restrict__ x, const float* __restrict__ Wr,
    const float* __restrict__ br, unsigned short* __restrict__ xb,
    int* __restrict__ top2i, float* __restrict__ gates2)
{
    __shared__ float xs[64][68];   // [token][k] fp32 tile (pad 68 vs bank conflicts)
    __shared__ float wT[64][68];   // [expert][k] transposed Wr tile
    const int tid = threadIdx.x;
    const int t0  = blockIdx.x * 64;
    const int tm  = tid >> 4;     // 0..15 token group
    const int te  = tid & 15;     // 0..15 expert group

    float acc[4][4];
#pragma unroll
    for (int i = 0; i < 4; i++)
#pragma unroll
        for (int j = 0; j < 4; j++) acc[i][j] = 0.f;

    for (int ks = 0; ks < DIM; ks += 64) {
        __syncthreads();
        // stage x tile (and emit bf16 copy of x while it's in registers)
#pragma unroll
        for (int l = 0; l < 4; l++) {
            int row = l * 16 + tm;
            int col = te * 4;
            float4 v = *(const float4*)(x + (size_t)(t0 + row) * DIM + ks + col);
            *(float4*)&xs[row][col] = v;
            ushort4 b = make_ushort4(f2bf(v.x), f2bf(v.y), f2bf(v.z), f2bf(v.w));
            *(ushort4*)(xb + (size_t)(t0 + row) * DIM + ks + col) = b;
        }
        // stage Wr tile transposed: wT[e][k]
#pragma unroll
        for (int l = 0; l < 4; l++) {
            int kr = l * 16 + tm;
            int ec = te * 4;
            float4 v = *(const float4*)(Wr + (size_t)(ks + kr) * NEXP + ec);
            wT[ec + 0][kr] = v.x; wT[ec + 1][kr] = v.y;
            wT[ec + 2][kr] = v.z; wT[ec + 3][kr] = v.w;
        }
        __syncthreads();
#pragma unroll 4
        for (int kk = 0; kk < 64; kk += 4) {
            float4 xv[4], wv[4];
#pragma unroll
            for (int i = 0; i < 4; i++) xv[i] = *(float4*)&xs[tm + i * 16][kk];
#pragma unroll
            for (int j = 0; j < 4; j++) wv[j] = *(float4*)&wT[te + j * 16][kk];
#pragma unroll
            for (int i = 0; i < 4; i++)
#pragma unroll
                for (int j = 0; j < 4; j++)
                    acc[i][j] += xv[i].x * wv[j].x + xv[i].y * wv[j].y +
                                 xv[i].z * wv[j].z + xv[i].w * wv[j].w;
        }
    }
    __syncthreads();
    // dump logits (+bias) into xs, then one thread per token does top-2
#pragma unroll
    for (int i = 0; i < 4; i++)
#pragma unroll
        for (int j = 0; j < 4; j++)
            xs[tm + i * 16][te + j * 16] = acc[i][j] + br[te + j * 16];
    __syncthreads();
    if (tid < 64) {
        int n = t0 + tid;
        float v1 = -1e30f, v2 = -1e30f; int i1 = 0, i2 = 0;
        for (int e = 0; e < 64; e++) {
            float v = xs[tid][e];
            if (v > v1)      { v2 = v1; i2 = i1; v1 = v; i1 = e; }
            else if (v > v2) { v2 = v;  i2 = e; }
        }
        float g0 = 1.f / (1.f + expf(v2 - v1));   // softmax over (v1,v2), v1>=v2
        top2i[n * 2 + 0] = i1; top2i[n * 2 + 1] = i2;
        gates2[n * 2 + 0] = g0; gates2[n * 2 + 1] = 1.f - g0;
    }
}

// ---------------------------------------------------------------------------
// Phase 2a: per-chunk expert histograms. Position p = k*N + n (k-major order,
// matching the reference's transpose(1,0).flatten() + cumsum semantics).
// ---------------------------------------------------------------------------
__global__ __launch_bounds__(256) void hist_kernel(
    const int* __restrict__ top2i, int* __restrict__ hist)
{
    __shared__ int cnt[NEXP];
    int tid = threadIdx.x;
    if (tid < NEXP) cnt[tid] = 0;
    __syncthreads();
    int p = blockIdx.x * 256 + tid;
    int k = p >> 14, n = p & 16383;
    int e = top2i[n * 2 + k];
    atomicAdd(&cnt[e], 1);
    __syncthreads();
    if (tid < NEXP) hist[blockIdx.x * NEXP + tid] = cnt[tid];
}

// Phase 2b: exclusive scan over chunks per expert + clamped totals.
__global__ __launch_bounds__(64) void scan_kernel(
    const int* __restrict__ hist, int* __restrict__ pre, int* __restrict__ cntc)
{
    int e = threadIdx.x;
    int run = 0;
#pragma unroll 8
    for (int c = 0; c < 128; c++) {
        pre[c * NEXP + e] = run;
        run += hist[c * NEXP + e];
    }
    cntc[e] = run < CAPACITY ? run : CAPACITY;
}

// Phase 2c: stable intra-chunk ranks via wave ballot; build per-expert lists.
__global__ __launch_bounds__(64) void rank_kernel(
    const int* __restrict__ top2i, const float* __restrict__ gates2,
    const int* __restrict__ pre, int* __restrict__ list_tok,
    float* __restrict__ list_gate)
{
    int lane = threadIdx.x;
    int c = blockIdx.x;
    int cnt_reg = pre[c * NEXP + lane];            // lane e owns expert e's counter
    unsigned long long below = (1ull << lane) - 1ull;
    for (int r = 0; r < 4; r++) {                  // 4 x 64 = 256 positions, in order
        int p = c * 256 + r * 64 + lane;
        int k = p >> 14, n = p & 16383;
        int e = top2i[n * 2 + k];
        int slot = 0;
#pragma unroll 1
        for (int q = 0; q < NEXP; q++) {
            unsigned long long mask = __ballot(e == q);
            int base = __shfl(cnt_reg, q);
            if (e == q) slot = base + __popcll(mask & below);
            if (lane == q) cnt_reg += (int)__popcll(mask);
        }
        if (slot < CAPACITY) {
            list_tok[e * CAPACITY + slot]  = n;
            list_gate[e * CAPACITY + slot] = gates2[n * 2 + k];
        }
    }
}

// ---------------------------------------------------------------------------
// Phase 3: grouped expert GEMM, bf16 MFMA 16x16x32, 128x128 tile, BK=32.
// A = gathered bf16 token rows; B = We fp32 staged w/ in-register transpose
// into B^T LDS layout. Epilogue: atomicAdd(out[token], gate*relu(v)).
// ---------------------------------------------------------------------------
#define MT 128
#define NT 128
#define BK 32
#define LDA 36   // shorts per LDS row: 32 + 4 pad (72 B, conflict-friendly)

__global__ __launch_bounds__(256) void moe_gemm(
    const unsigned short* __restrict__ xb, const float* __restrict__ We,
    const int* __restrict__ list_tok, const float* __restrict__ list_gate,
    const int* __restrict__ cntc, float* __restrict__ out)
{
    const int bid = blockIdx.x;
    const int e   = bid / 40;
    const int rem = bid % 40;
    const int mt  = rem >> 3;   // 0..4  (5 M-tiles over CAP=640)
    const int nt  = rem & 7;    // 0..7  (8 N-tiles over D=1024)
    const int cnt = cntc[e];
    if (mt * MT >= cnt) return;
    int valid = cnt - mt * MT; if (valid > MT) valid = MT;

    __shared__ unsigned short As[MT * LDA];
    __shared__ unsigned short Bs[NT * LDA];   // B^T: [n][k]
    __shared__ int   tok_s[MT];
    __shared__ float gate_s[MT];

    const int tid = threadIdx.x;
    if (tid < MT) {
        int slot = mt * MT + tid;
        bool v = tid < valid;
        tok_s[tid]  = v ? list_tok[e * CAPACITY + slot]  : list_tok[e * CAPACITY];
        gate_s[tid] = v ? list_gate[e * CAPACITY + slot] : 0.f;
    }
    __syncthreads();

    // A staging map: thread -> (row = tid>>1, 16-element half = tid&1)
    const int arow = tid >> 1, ah = tid & 1;
    const unsigned short* aptr = xb + (size_t)tok_s[arow] * DIM + ah * 16;
    // B staging map: thread -> 4 cols (n) x 4 rows (k) micro-block
    const int bn0 = (tid & 31) * 4;
    const int bkr = (tid >> 5) * 4;
    const float* bptr = We + (size_t)e * DIM * DIM + (size_t)bkr * DIM + nt * NT + bn0;

    f32x4 acc[4][4];
#pragma unroll
    for (int i = 0; i < 4; i++)
#pragma unroll
        for (int j = 0; j < 4; j++) acc[i][j] = (f32x4){0.f, 0.f, 0.f, 0.f};

    const int lane = tid & 63, wave = tid >> 6;
    const int wm = wave >> 1, wn = wave & 1;
    const int fm = lane & 15, kq = lane >> 4;

    for (int ks = 0; ks < DIM; ks += BK) {
        __syncthreads();
        // ---- stage A: 32 B per thread (gathered bf16 token row segment)
        uint4 a0 = *(const uint4*)(aptr + ks);
        uint4 a1 = *(const uint4*)(aptr + ks + 8);
        {
            unsigned short* d = &As[arow * LDA + ah * 16];
            *(uint2*)(d + 0)  = make_uint2(a0.x, a0.y);
            *(uint2*)(d + 4)  = make_uint2(a0.z, a0.w);
            *(uint2*)(d + 8)  = make_uint2(a1.x, a1.y);
            *(uint2*)(d + 12) = make_uint2(a1.z, a1.w);
        }
        // ---- stage B: load 4x4 fp32 block, transpose+convert, write B^T bf16
        {
            float4 b[4];
#pragma unroll
            for (int j = 0; j < 4; j++)
                b[j] = *(const float4*)(bptr + (size_t)(ks + j) * DIM);
            union { float4 v; float f[4]; } u0, u1, u2, u3;
            u0.v = b[0]; u1.v = b[1]; u2.v = b[2]; u3.v = b[3];
#pragma unroll
            for (int cc = 0; cc < 4; cc++) {
                unsigned int lo = (unsigned int)f2bf(u0.f[cc]) | ((unsigned int)f2bf(u1.f[cc]) << 16);
                unsigned int hi = (unsigned int)f2bf(u2.f[cc]) | ((unsigned int)f2bf(u3.f[cc]) << 16);
                *(uint2*)&Bs[(bn0 + cc) * LDA + bkr] = make_uint2(lo, hi);
            }
        }
        __syncthreads();
        // ---- fragments + MFMA
        union { uint2 u[2]; bf16x8 v; } fa[4], fb[4];
#pragma unroll
        for (int i = 0; i < 4; i++) {
            const unsigned short* s = &As[(wm * 64 + i * 16 + fm) * LDA + kq * 8];
            fa[i].u[0] = *(const uint2*)(s);
            fa[i].u[1] = *(const uint2*)(s + 4);
        }
#pragma unroll
        for (int j = 0; j < 4; j++) {
            const unsigned short* s = &Bs[(wn * 64 + j * 16 + fm) * LDA + kq * 8];
            fb[j].u[0] = *(const uint2*)(s);
            fb[j].u[1] = *(const uint2*)(s + 4);
        }
#pragma unroll
        for (int i = 0; i < 4; i++)
#pragma unroll
            for (int j = 0; j < 4; j++)
                acc[i][j] = __builtin_amdgcn_mfma_f32_16x16x32_bf16(
                    fa[i].v, fb[j].v, acc[i][j], 0, 0, 0);
    }

    // ---- epilogue: relu * gate, scatter-add into out[token]
    // C/D layout (m89/m91): col = lane&15, row = (lane>>4)*4 + reg
    const int col0 = nt * NT + wn * 64 + fm;
#pragma unroll
    for (int i = 0; i < 4; i++) {
        int rbase = wm * 64 + i * 16 + kq * 4;
#pragma unroll
        for (int j = 0; j < 4; j++) {
            int col = col0 + j * 16;
#pragma unroll
            for (int r = 0; r < 4; r++) {
                int row = rbase + r;
                if (row < valid) {
                    float v = acc[i][j][r];
                    v = fmaxf(v, 0.f) * gate_s[row];
                    atomicAdd(out + (size_t)tok_s[row] * DIM + col, v);
                }
            }
        }
    }
}

// ---------------------------------------------------------------------------
extern "C" void kernel_launch(void* const* d_in, const int* in_sizes, int n_in,
                              void* d_out, int out_size, void* d_ws, size_t ws_size,
                              hipStream_t stream)
{
    const float* x  = (const float*)d_in[0];
    const float* Wr = (const float*)d_in[1];
    const float* br = (const float*)d_in[2];
    const float* We = (const float*)d_in[3];
    float* out = (float*)d_out;

    char* ws = (char*)d_ws;
    size_t off = 0;
    unsigned short* xb = (unsigned short*)(ws + off); off += (size_t)N_TOK * DIM * 2;
    int*   top2i     = (int*)(ws + off);   off += (size_t)N_TOK * 2 * 4;
    float* gates2    = (float*)(ws + off); off += (size_t)N_TOK * 2 * 4;
    int*   hist      = (int*)(ws + off);   off += 128 * NEXP * 4;
    int*   pre       = (int*)(ws + off);   off += 128 * NEXP * 4;
    int*   cntc      = (int*)(ws + off);   off += NEXP * 4;
    int*   list_tok  = (int*)(ws + off);   off += NEXP * CAPACITY * 4;
    float* list_gate = (float*)(ws + off); off += NEXP * CAPACITY * 4;

    hipMemsetAsync(out, 0, (size_t)N_TOK * DIM * 4, stream);
    router_kernel<<<N_TOK / 64, 256, 0, stream>>>(x, Wr, br, xb, top2i, gates2);
    hist_kernel<<<128, 256, 0, stream>>>(top2i, hist);
    scan_kernel<<<1, 64, 0, stream>>>(hist, pre, cntc);
    rank_kernel<<<128, 64, 0, stream>>>(top2i, gates2, pre, list_tok, list_gate);
    moe_gemm<<<NEXP * 40, 256, 0, stream>>>(xb, We, list_tok, list_gate, cntc, out);
}